// Round 5
// baseline (89.888 us; speedup 1.0000x reference)
//
#include <hip/hip_runtime.h>

typedef __attribute__((ext_vector_type(8))) short bf16x8;
typedef __attribute__((ext_vector_type(4))) float f32x4;

#define B_    2048
#define S_    512

// ws layout (bytes)
#define OFF_WT1   0u          // 512*128*2  = 131072   Wt1[n][k] (transposed, k<100 real)
#define OFF_WT2   131072u     // 512*512*2  = 524288   Wt2[n][k]
#define OFF_WT3   655360u     // 512*512*2  = 524288   Wt3[n][k]
#define OFF_WTF   1179648u    // 16*512*2   = 16384    Wtf[n][k], n<2 real
#define OFF_PREF  1196032u    // 512*64*4   = 131072   float pref[512][64] (50 used)
#define OFF_EMBB  1327104u    // 50000*64*2 = 6400000  bf16 emb, padded 50->64 (one 128B line/row)
#define WS_NEED   (OFF_EMBB + 6400000u)

__device__ __forceinline__ unsigned short f2bf(float f) {
    unsigned int u = __float_as_uint(f);
    u += 0x7FFFu + ((u >> 16) & 1u);          // round-to-nearest-even
    return (unsigned short)(u >> 16);
}

#define MFMA16(a, b, c) __builtin_amdgcn_mfma_f32_16x16x32_bf16((a), (b), (c), 0, 0, 0)

// ---------------- prep_convert: weights->bf16^T, pos-prefix, emb->bf16 -------
__global__ __launch_bounds__(256) void prep_convert(
    const float* __restrict__ W1, const float* __restrict__ W2,
    const float* __restrict__ W3, const float* __restrict__ Wf,
    const float* __restrict__ post, const int* __restrict__ pos,
    const float* __restrict__ emb,
    unsigned short* __restrict__ ws, float* __restrict__ pref, int do_emb)
{
    const int bid = blockIdx.x;
    const int tid = threadIdx.x;

    if (bid < 152) {                      // ---- weight transpose-convert
        __shared__ float tile[64][65];
        const float* src; unsigned short* dst;
        int k0, n0, Ksrc, Nsrc, Kpad, Ndst;
        if (bid < 64)       { src = W2; dst = ws + OFF_WT2/2; k0 = (bid>>3)*64;  n0 = (bid&7)*64;  Ksrc = 512; Nsrc = 512; Kpad = 512; Ndst = 512; }
        else if (bid < 128) { int b = bid-64;  src = W3; dst = ws + OFF_WT3/2; k0 = (b>>3)*64; n0 = (b&7)*64; Ksrc = 512; Nsrc = 512; Kpad = 512; Ndst = 512; }
        else if (bid < 144) { int b = bid-128; src = W1; dst = ws + OFF_WT1/2; k0 = (b>>3)*64; n0 = (b&7)*64; Ksrc = 100; Nsrc = 512; Kpad = 128; Ndst = 512; }
        else                { int b = bid-144; src = Wf; dst = ws + OFF_WTF/2; k0 = b*64;      n0 = 0;        Ksrc = 512; Nsrc = 2;   Kpad = 512; Ndst = 16;  }

        const int c  = tid & 63;
        const int r4 = tid >> 6;
#pragma unroll
        for (int rr = 0; rr < 16; ++rr) {
            int r = rr*4 + r4;
            float v = 0.f;
            if (k0 + r < Ksrc && n0 + c < Nsrc) v = src[(size_t)(k0+r)*Nsrc + n0 + c];
            tile[r][c] = v;
        }
        __syncthreads();
#pragma unroll
        for (int rr = 0; rr < 16; ++rr) {
            int nrow = rr*4 + r4;
            if (n0 + nrow < Ndst)
                dst[(size_t)(n0+nrow)*Kpad + k0 + c] = f2bf(tile[c][nrow]);
        }
    } else if (bid == 152) {              // ---- pos-prefix (parallel, 4 chunks)
        __shared__ int   idx_s[512];
        __shared__ float csum[4][52];
        idx_s[tid]       = pos[tid];
        idx_s[tid + 256] = pos[tid + 256];
        __syncthreads();
        const int c = tid >> 6, d = tid & 63;
        if (d < 50) {
            float run = 0.f;
            for (int s = c*128; s < c*128 + 128; ++s)
                run += post[(size_t)idx_s[s]*50 + d];
            csum[c][d] = run;
        }
        __syncthreads();
        if (d < 50) {
            float run = 0.f;
            for (int cc = 0; cc < c; ++cc) run += csum[cc][d];
            for (int s = c*128; s < c*128 + 128; ++s) {
                run += post[(size_t)idx_s[s]*50 + d];
                pref[(size_t)s*64 + d] = run;
            }
        }
    } else {                              // ---- emb fp32 -> bf16, 64-padded rows
        if (!do_emb) return;
        unsigned short* embb = ws + OFF_EMBB/2;
        const int blk = bid - 153;                   // 0..390
        const int r0  = blk * 128;
        if (r0 >= 50000) return;
        const int nr = min(128, 50000 - r0);
        for (int i = tid; i < nr * 64; i += 256) {
            int r = i >> 6, d = i & 63;
            float v = (d < 50) ? emb[(size_t)(r0 + r)*50 + d] : 0.f;
            embb[(size_t)(r0 + r)*64 + d] = f2bf(v);
        }
    }
}

// ---------------- MFMA helpers ------------------------------------------------
__device__ __forceinline__ void load_afrags(bf16x8 (&a)[16],
    const unsigned short* h, int row, int kq)
{
#pragma unroll
    for (int ks = 0; ks < 16; ++ks)
        a[ks] = *(const bf16x8*)((const char*)h +
                  (((unsigned)(row * 1024 + ks * 64 + kq * 16)) ^ ((row & 7) << 4)));
}

__device__ __forceinline__ void store_h(unsigned short* h, const f32x4 (&acc)[4],
    const float (&bb)[4], int wave, int row, int kq)
{
#pragma unroll
    for (int nt = 0; nt < 4; ++nt) {
        int c = wave*64 + nt*16 + row;
#pragma unroll
        for (int r4 = 0; r4 < 4; ++r4) {
            int hrow = kq*4 + r4;
            unsigned base = hrow * 1024;
            *(unsigned short*)((char*)h + ((base + c*2) ^ ((hrow & 7) << 4))) =
                f2bf(fmaxf(acc[nt][r4] + bb[nt], 0.f));
        }
    }
}

// stage one BK=32 weight chunk (32 KB) into Bst buffer gk%3 via global_load_lds.
// LDS chunk layout: [kq(4)][n(512)][16B] -> ds_read_b128 conflict-free, src linear.
__device__ __forceinline__ void stage_gk(int gk,
    const unsigned short* __restrict__ Wt2, const unsigned short* __restrict__ Wt3,
    char* BstC, int tid)
{
    const unsigned short* Wt = (gk < 16) ? Wt2 : Wt3;
    const int kc = gk & 15;
    char* buf = BstC + (gk % 3) * 32768;
#pragma unroll
    for (int j = 0; j < 4; ++j) {
        unsigned X = (unsigned)j*8192u + (unsigned)tid*16u;   // byte in 32KB chunk
        unsigned n = (X & 8191u) >> 4;                        // col index
        const char* src = (const char*)Wt + (size_t)n*1024u + (unsigned)kc*64u + (unsigned)j*16u;
        __builtin_amdgcn_global_load_lds(
            (const __attribute__((address_space(1))) unsigned int*)src,
            (__attribute__((address_space(3))) unsigned int*)(buf + X),
            16, 0, 0);
    }
}

// ---------------- dan_fused: pooling + 4-layer MFMA MLP ----------------------
// 256 blocks x 512 threads (1/CU). Wave w pools row b0+w: lane d owns dim d,
// one coalesced 128B-line ushort load per token, 32 deep. Then M=16(8 real)
// MLP; W2/W3 streamed through LDS (BK=32, 3 bufs, 2-ahead, counted vmcnt).
template<int EMODE>     // 0 = padded bf16 table in ws, 1 = fallback fp32
__global__ __launch_bounds__(512) void dan_fused(
    const float* __restrict__ emb, const int* __restrict__ seq,
    const int* __restrict__ seqlen, const unsigned short* __restrict__ ws_ro,
    const float* __restrict__ pref,
    const float* __restrict__ b1, const float* __restrict__ b2,
    const float* __restrict__ b3, const float* __restrict__ bfin,
    float* __restrict__ out)
{
    __shared__ __align__(16) unsigned short idx_s[8*512];     // 8 KB
    __shared__ __align__(16) unsigned short pooled_s[16*144]; // 4.6 KB
    __shared__ __align__(16) unsigned short hA[8192];         // 16 KB
    __shared__ __align__(16) unsigned short hB[8192];         // 16 KB
    __shared__ __align__(16) unsigned short Bst[3*16384];     // 96 KB

    const int tid  = threadIdx.x;
    const int wave = tid >> 6;
    const int lane = tid & 63;
    const int row  = lane & 15;
    const int kq   = lane >> 4;
    const int b0   = blockIdx.x * 8;

    const unsigned short* Wt1 = ws_ro + OFF_WT1 / 2;
    const unsigned short* Wt2 = ws_ro + OFF_WT2 / 2;
    const unsigned short* Wt3 = ws_ro + OFF_WT3 / 2;
    const unsigned short* Wtf = ws_ro + OFF_WTF / 2;
    char* BstC = (char*)Bst;

    // stage indices (ushort: vocab < 65536) + zero pooled_s
    for (int i = tid; i < 8*512; i += 512)
        idx_s[i] = (unsigned short)seq[(size_t)b0 * S_ + i];
    for (int i = tid; i < 16*144; i += 512) pooled_s[i] = 0;

    // W1 fragments preloaded (hide behind pooling)
    bf16x8 w1f[4][4];
#pragma unroll
    for (int ci = 0; ci < 4; ++ci) {
        const unsigned short* p = Wt1 + (size_t)(wave*64 + ci*16 + row) * 128 + kq*8;
#pragma unroll
        for (int ks = 0; ks < 4; ++ks) w1f[ci][ks] = *(const bf16x8*)(p + ks * 32);
    }
    __syncthreads();

    // ---- pooling: wave w -> row b0+w; lane d accumulates dim d
    const int L = seqlen[b0 + wave];
    const unsigned short* idxr = idx_s + wave * 512;
    float a4[4] = {0.f, 0.f, 0.f, 0.f};

    if (EMODE == 0) {
        const unsigned short* tb = ws_ro + OFF_EMBB / 2;
        const int Lfull = L & ~31;
        for (int s0 = 0; s0 < Lfull; s0 += 32) {
#pragma unroll
            for (int j = 0; j < 32; ++j) {
                int tok = idxr[s0 + j];                         // LDS broadcast
                unsigned short uv = tb[(size_t)(tok*64 + lane)];// 1 line/token, coalesced
                a4[j & 3] += __uint_as_float((unsigned)uv << 16);
            }
        }
        if (Lfull < L) {
#pragma unroll
            for (int j = 0; j < 32; ++j) {
                int s = Lfull + j;
                if (s < L) {
                    int tok = idxr[s];
                    unsigned short uv = tb[(size_t)(tok*64 + lane)];
                    a4[j & 3] += __uint_as_float((unsigned)uv << 16);
                }
            }
        }
    } else {
        for (int s0 = 0; s0 < L; s0 += 32) {
#pragma unroll
            for (int j = 0; j < 32; ++j) {
                int s = s0 + j;
                if (s < L) {
                    int tok = idxr[s];
                    float v = (lane < 50) ? emb[(size_t)tok*50 + lane] : 0.f;
                    a4[j & 3] += v;
                }
            }
        }
    }
    float acc = (a4[0] + a4[1]) + (a4[2] + a4[3]);
    if (lane < 50) {
        float Lf = (float)L;
        pooled_s[wave*144 + lane]      = f2bf(acc / Lf);
        pooled_s[wave*144 + 50 + lane] = f2bf(pref[(size_t)(L-1)*64 + lane] / Lf);
    }
    __syncthreads();

    // ---- Layer 1 (K=128) from pooled_s, weights in regs
    {
        bf16x8 a1[4];
#pragma unroll
        for (int ks = 0; ks < 4; ++ks)
            a1[ks] = *(const bf16x8*)&pooled_s[row*144 + ks*32 + kq*8];
#pragma unroll
        for (int ci = 0; ci < 4; ++ci) {
            const int c = wave*64 + ci*16 + row;
            f32x4 a0 = {0.f, 0.f, 0.f, 0.f};
#pragma unroll
            for (int ks = 0; ks < 4; ++ks) a0 = MFMA16(a1[ks], w1f[ci][ks], a0);
            const float bb = b1[c];
#pragma unroll
            for (int r4 = 0; r4 < 4; ++r4) {
                int hrow = kq*4 + r4;
                unsigned bofs = hrow * 1024;
                *(unsigned short*)((char*)hA + ((bofs + c*2) ^ ((hrow & 7) << 4))) =
                    f2bf(fmaxf(a0[r4] + bb, 0.f));
            }
        }
    }
    __syncthreads();

    // ---- Layers 2 & 3: staged LDS pipeline, BK=32, 3 bufs, 2 ahead
    bf16x8 a[16];
    load_afrags(a, hA, row, kq);
    f32x4 acc4[4];
#pragma unroll
    for (int nt = 0; nt < 4; ++nt) acc4[nt] = (f32x4){0.f, 0.f, 0.f, 0.f};
    float bb2[4];
#pragma unroll
    for (int nt = 0; nt < 4; ++nt) bb2[nt] = b2[wave*64 + nt*16 + row];

    asm volatile("s_waitcnt vmcnt(0)" ::: "memory");
    stage_gk(0, Wt2, Wt3, BstC, tid);
    stage_gk(1, Wt2, Wt3, BstC, tid);
    asm volatile("s_waitcnt vmcnt(4)" ::: "memory");
    __builtin_amdgcn_s_barrier();
    asm volatile("" ::: "memory");

    // layer 2: gk = kc (0..15)
#pragma unroll
    for (int kc = 0; kc < 16; ++kc) {
        stage_gk(kc + 2, Wt2, Wt3, BstC, tid);
        const char* bufc = BstC + (kc % 3) * 32768 + (kq << 13);
#pragma unroll
        for (int nt = 0; nt < 4; ++nt) {
            int c = wave*64 + nt*16 + row;
            bf16x8 bv = *(const bf16x8*)(bufc + (c << 4));
            acc4[nt] = MFMA16(a[kc], bv, acc4[nt]);
        }
        asm volatile("s_waitcnt vmcnt(4)" ::: "memory");
        __builtin_amdgcn_s_barrier();
        asm volatile("" ::: "memory");
    }

    // transition: hB = relu(acc+b2); reload A; (syncthreads drains stage 17 - ok)
    store_h(hB, acc4, bb2, wave, row, kq);
    __syncthreads();
    load_afrags(a, hB, row, kq);
    float bb3[4];
#pragma unroll
    for (int nt = 0; nt < 4; ++nt) bb3[nt] = b3[wave*64 + nt*16 + row];
#pragma unroll
    for (int nt = 0; nt < 4; ++nt) acc4[nt] = (f32x4){0.f, 0.f, 0.f, 0.f};
    asm volatile("s_waitcnt vmcnt(0)" ::: "memory");

    // layer 3: gk = 16+kc; chunks 16,17 already resident
#pragma unroll
    for (int kc = 0; kc < 16; ++kc) {
        const int gk = 16 + kc;
        if (kc < 14) stage_gk(gk + 2, Wt2, Wt3, BstC, tid);
        const char* bufc = BstC + (gk % 3) * 32768 + (kq << 13);
#pragma unroll
        for (int nt = 0; nt < 4; ++nt) {
            int c = wave*64 + nt*16 + row;
            bf16x8 bv = *(const bf16x8*)(bufc + (c << 4));
            acc4[nt] = MFMA16(a[kc], bv, acc4[nt]);
        }
        if (kc < 14) { asm volatile("s_waitcnt vmcnt(4)" ::: "memory"); }
        else         { asm volatile("s_waitcnt vmcnt(0)" ::: "memory"); }
        __builtin_amdgcn_s_barrier();
        asm volatile("" ::: "memory");
    }

    // layer-3 output -> hA, then final layer (wave 0)
    store_h(hA, acc4, bb3, wave, row, kq);
    __syncthreads();

    if (wave == 0) {
        load_afrags(a, hA, row, kq);
        f32x4 accf = {0.f, 0.f, 0.f, 0.f};
        const unsigned short* pw = Wtf + (size_t)row * 512 + kq * 8;
#pragma unroll
        for (int ks = 0; ks < 16; ++ks) {
            bf16x8 bv = *(const bf16x8*)(pw + ks * 32);
            accf = MFMA16(a[ks], bv, accf);
        }
        if (row < 2 && kq < 2) {
            float bb = bfin[row];
#pragma unroll
            for (int r4 = 0; r4 < 4; ++r4) {
                int m = kq*4 + r4;                   // real rows 0..7
                out[(size_t)(b0 + m) * 2 + row] = accf[r4] + bb;
            }
        }
    }
}

extern "C" void kernel_launch(void* const* d_in, const int* in_sizes, int n_in,
                              void* d_out, int out_size, void* d_ws, size_t ws_size,
                              hipStream_t stream)
{
    const float* emb    = (const float*)d_in[0];
    const float* post   = (const float*)d_in[1];
    const float* W1     = (const float*)d_in[2];
    const float* b1     = (const float*)d_in[3];
    const float* W2     = (const float*)d_in[4];
    const float* b2     = (const float*)d_in[5];
    const float* W3     = (const float*)d_in[6];
    const float* b3     = (const float*)d_in[7];
    const float* Wf     = (const float*)d_in[8];
    const float* bf     = (const float*)d_in[9];
    const int*   seq    = (const int*)d_in[10];
    const int*   seqlen = (const int*)d_in[11];
    const int*   pos    = (const int*)d_in[12];
    float*       out    = (float*)d_out;

    unsigned short* ws = (unsigned short*)d_ws;
    float* pref = (float*)((char*)d_ws + OFF_PREF);
    const int do_emb = (ws_size >= (size_t)WS_NEED) ? 1 : 0;

    prep_convert<<<544, 256, 0, stream>>>(W1, W2, W3, Wf, post, pos, emb,
                                          ws, pref, do_emb);
    if (do_emb)
        dan_fused<0><<<B_ / 8, 512, 0, stream>>>(emb, seq, seqlen, ws, pref,
                                                 b1, b2, b3, bf, out);
    else
        dan_fused<1><<<B_ / 8, 512, 0, stream>>>(emb, seq, seqlen, ws, pref,
                                                 b1, b2, b3, bf, out);
}

// Round 6
// 47.760 us; speedup vs baseline: 1.8821x; 1.8821x over previous
//
#include <hip/hip_runtime.h>

typedef __attribute__((ext_vector_type(8))) short bf16x8;
typedef __attribute__((ext_vector_type(4))) float f32x4;

#define B_    2048
#define S_    512

// ws layout (bytes)
#define OFF_WF1   0u          // Wfrag1[32 ntile][4 ks][64 lane][8] bf16 = 131072
#define OFF_WF2   131072u     // Wfrag2[32][16][64][8] = 524288
#define OFF_WF3   655360u     // Wfrag3[32][16][64][8] = 524288
#define OFF_WFF   1179648u    // WfragF[16 ks][64][8]  = 16384 (cols>=2 zero)
#define OFF_PREF  1196032u    // float pref[512][64] (50 used)
#define OFF_EMBB  1327104u    // bf16 emb [50000][64] (one 128B line per row)
#define WS_NEED   (OFF_EMBB + 6400000u)

__device__ __forceinline__ unsigned short f2bf(float f) {
    unsigned int u = __float_as_uint(f);
    u += 0x7FFFu + ((u >> 16) & 1u);          // round-to-nearest-even
    return (unsigned short)(u >> 16);
}

#define MFMA16(a, b, c) __builtin_amdgcn_mfma_f32_16x16x32_bf16((a), (b), (c), 0, 0, 0)

// ---------------- prep_convert: weights->fragment-order bf16, pos-prefix, emb
// Fragment word (ntile, ks, lane) elem j = W[k = ks*32 + (lane>>4)*8 + j][n = ntile*16 + (lane&15)]
// -> a wave's B-fragment load is ONE coalesced 1KB dwordx4 (lane-contiguous).
__global__ __launch_bounds__(256) void prep_convert(
    const float* __restrict__ W1, const float* __restrict__ W2,
    const float* __restrict__ W3, const float* __restrict__ Wf,
    const float* __restrict__ post, const int* __restrict__ pos,
    const float* __restrict__ emb,
    unsigned short* __restrict__ ws, float* __restrict__ pref, int do_emb)
{
    const int bid = blockIdx.x;
    const int tid = threadIdx.x;

    if (bid < 152) {                      // ---- weight convert, 64x64 (k,n) tile
        __shared__ float tile[64][65];
        const float* src; unsigned short* dst;
        int k0, n0, Ksrc, Nsrc, ksTot, nTiles;
        if (bid < 64)       { src=W2; dst=ws+OFF_WF2/2; k0=(bid>>3)*64; n0=(bid&7)*64; Ksrc=512; Nsrc=512; ksTot=16; nTiles=4; }
        else if (bid < 128) { int b=bid-64;  src=W3; dst=ws+OFF_WF3/2; k0=(b>>3)*64; n0=(b&7)*64; Ksrc=512; Nsrc=512; ksTot=16; nTiles=4; }
        else if (bid < 144) { int b=bid-128; src=W1; dst=ws+OFF_WF1/2; k0=(b>>3)*64; n0=(b&7)*64; Ksrc=100; Nsrc=512; ksTot=4;  nTiles=4; }
        else                { int b=bid-144; src=Wf; dst=ws+OFF_WFF/2; k0=b*64;      n0=0;        Ksrc=512; Nsrc=2;   ksTot=16; nTiles=1; }

        const int c  = tid & 63;
        const int r4 = tid >> 6;
#pragma unroll
        for (int rr = 0; rr < 16; ++rr) {
            int r = rr*4 + r4;
            float v = 0.f;
            if (k0 + r < Ksrc && n0 + c < Nsrc) v = src[(size_t)(k0+r)*Nsrc + n0 + c];
            tile[r][c] = v;
        }
        __syncthreads();
        const int nWords = nTiles * 2 * 64;
        for (int w = tid; w < nWords; w += 256) {
            int lane = w & 63, ks_l = (w >> 6) & 1, nt_l = w >> 7;
            int kr = ks_l*32 + ((lane >> 4) << 3);
            int nc = nt_l*16 + (lane & 15);
            uint4 wv;
            wv.x = (unsigned)f2bf(tile[kr+0][nc]) | ((unsigned)f2bf(tile[kr+1][nc]) << 16);
            wv.y = (unsigned)f2bf(tile[kr+2][nc]) | ((unsigned)f2bf(tile[kr+3][nc]) << 16);
            wv.z = (unsigned)f2bf(tile[kr+4][nc]) | ((unsigned)f2bf(tile[kr+5][nc]) << 16);
            wv.w = (unsigned)f2bf(tile[kr+6][nc]) | ((unsigned)f2bf(tile[kr+7][nc]) << 16);
            int ntile = (n0 >> 4) + nt_l, ks = (k0 >> 5) + ks_l;
            ((uint4*)dst)[(size_t)(ntile*ksTot + ks)*64 + lane] = wv;
        }
    } else if (bid == 152) {              // ---- pos-prefix (parallel, 4 chunks)
        __shared__ int   idx_s[512];
        __shared__ float csum[4][52];
        idx_s[tid]       = pos[tid];
        idx_s[tid + 256] = pos[tid + 256];
        __syncthreads();
        const int c = tid >> 6, d = tid & 63;
        if (d < 50) {
            float run = 0.f;
            for (int s = c*128; s < c*128 + 128; ++s)
                run += post[(size_t)idx_s[s]*50 + d];
            csum[c][d] = run;
        }
        __syncthreads();
        if (d < 50) {
            float run = 0.f;
            for (int cc = 0; cc < c; ++cc) run += csum[cc][d];
            for (int s = c*128; s < c*128 + 128; ++s) {
                run += post[(size_t)idx_s[s]*50 + d];
                pref[(size_t)s*64 + d] = run;
            }
        }
    } else {                              // ---- emb fp32 -> bf16, 64-padded rows
        if (!do_emb) return;
        unsigned short* embb = ws + OFF_EMBB/2;
        const int blk = bid - 153;                   // 0..390
        const int r0  = blk * 128;
        if (r0 >= 50000) return;
        const int nr = min(128, 50000 - r0);
        for (int i = tid; i < nr * 64; i += 256) {
            int r = i >> 6, d = i & 63;
            float v = (d < 50) ? emb[(size_t)(r0 + r)*50 + d] : 0.f;
            embb[(size_t)(r0 + r)*64 + d] = f2bf(v);
        }
    }
}

// ---------------- MFMA helpers (swizzled LDS h-tiles, verified r2-r5) --------
__device__ __forceinline__ void load_afrags(bf16x8 (&a)[16],
    const unsigned short* h, int row, int kq)
{
#pragma unroll
    for (int ks = 0; ks < 16; ++ks)
        a[ks] = *(const bf16x8*)((const char*)h +
                  (((unsigned)(row * 1024 + ks * 64 + kq * 16)) ^ ((row & 7) << 4)));
}

__device__ __forceinline__ void store_h(unsigned short* h, const f32x4 (&acc)[4],
    const float (&bb)[4], int wave, int row, int kq)
{
#pragma unroll
    for (int nt = 0; nt < 4; ++nt) {
        int c = wave*64 + nt*16 + row;
#pragma unroll
        for (int r4 = 0; r4 < 4; ++r4) {
            int hrow = kq*4 + r4;
            unsigned base = hrow * 1024;
            *(unsigned short*)((char*)h + ((base + c*2) ^ ((hrow & 7) << 4))) =
                f2bf(fmaxf(acc[nt][r4] + bb[nt], 0.f));
        }
    }
}

// one 512x512 layer: wave owns ntiles wave*4..+3; coalesced fragment loads,
// double-buffered bv arrays, no barriers inside.
__device__ __forceinline__ void layer512(
    const bf16x8 (&a)[16], const unsigned short* __restrict__ Wfrag,
    const float* __restrict__ bias, unsigned short* hout,
    int wave, int row, int kq, int lane)
{
    const bf16x8* bp = (const bf16x8*)Wfrag + ((size_t)(wave*4) * 16 * 64) + lane;
    float bb[4];
#pragma unroll
    for (int nt = 0; nt < 4; ++nt) bb[nt] = bias[wave*64 + nt*16 + row];

    bf16x8 bvA[16], bvB[16];
#pragma unroll
    for (int ks = 0; ks < 16; ++ks) bvA[ks] = bp[(0*16 + ks)*64];
#pragma unroll
    for (int ks = 0; ks < 16; ++ks) bvB[ks] = bp[(1*16 + ks)*64];

    f32x4 acc[4];
    acc[0] = (f32x4){0.f,0.f,0.f,0.f};
#pragma unroll
    for (int ks = 0; ks < 16; ++ks) acc[0] = MFMA16(a[ks], bvA[ks], acc[0]);
#pragma unroll
    for (int ks = 0; ks < 16; ++ks) bvA[ks] = bp[(2*16 + ks)*64];

    acc[1] = (f32x4){0.f,0.f,0.f,0.f};
#pragma unroll
    for (int ks = 0; ks < 16; ++ks) acc[1] = MFMA16(a[ks], bvB[ks], acc[1]);
#pragma unroll
    for (int ks = 0; ks < 16; ++ks) bvB[ks] = bp[(3*16 + ks)*64];

    acc[2] = (f32x4){0.f,0.f,0.f,0.f};
#pragma unroll
    for (int ks = 0; ks < 16; ++ks) acc[2] = MFMA16(a[ks], bvA[ks], acc[2]);
    acc[3] = (f32x4){0.f,0.f,0.f,0.f};
#pragma unroll
    for (int ks = 0; ks < 16; ++ks) acc[3] = MFMA16(a[ks], bvB[ks], acc[3]);

    store_h(hout, acc, bb, wave, row, kq);
}

// ---------------- dan_fused: pooling + 4-layer MFMA MLP ----------------------
// 256 blocks x 512 threads. Pooling: wave w -> row b0+w, 8 lanes per token
// (one 128B line per token, fully consumed), 8 uint4 in flight, shfl reduce.
// MLP: M=16 (8 real), fragment-ordered coalesced weight loads, no in-layer sync.
template<int EMODE>     // 0 = padded bf16 table in ws, 1 = fallback fp32
__global__ __launch_bounds__(512, 2) void dan_fused(
    const float* __restrict__ emb, const int* __restrict__ seq,
    const int* __restrict__ seqlen, const unsigned short* __restrict__ ws_ro,
    const float* __restrict__ pref,
    const float* __restrict__ b1, const float* __restrict__ b2,
    const float* __restrict__ b3, const float* __restrict__ bfin,
    float* __restrict__ out)
{
    __shared__ __align__(16) unsigned short idx_s[8*512];     // 8 KB
    __shared__ __align__(16) unsigned short pooled_s[16*144]; // 4.6 KB
    __shared__ __align__(16) unsigned short hA[8192];         // 16 KB
    __shared__ __align__(16) unsigned short hB[8192];         // 16 KB

    const int tid  = threadIdx.x;
    const int wave = tid >> 6;
    const int lane = tid & 63;
    const int row  = lane & 15;
    const int kq   = lane >> 4;
    const int b0   = blockIdx.x * 8;

    const unsigned short* WF1 = ws_ro + OFF_WF1 / 2;
    const unsigned short* WF2 = ws_ro + OFF_WF2 / 2;
    const unsigned short* WF3 = ws_ro + OFF_WF3 / 2;
    const unsigned short* WFF = ws_ro + OFF_WFF / 2;

    for (int i = tid; i < 8*512; i += 512)
        idx_s[i] = (unsigned short)seq[(size_t)b0 * S_ + i];
    for (int i = tid; i < 16*144; i += 512) pooled_s[i] = 0;

    // W1 fragments: 16 coalesced 16B loads per wave (hide behind pooling)
    bf16x8 w1f[4][4];
    {
        const bf16x8* bp1 = (const bf16x8*)WF1 + ((size_t)(wave*4) * 4 * 64) + lane;
#pragma unroll
        for (int ci = 0; ci < 4; ++ci)
#pragma unroll
            for (int ks = 0; ks < 4; ++ks) w1f[ci][ks] = bp1[(ci*4 + ks)*64];
    }
    __syncthreads();

    // ---- pooling
    const int L = seqlen[b0 + wave];
    const float Lf = (float)L;
    const unsigned short* idxr = idx_s + wave * 512;

    if (EMODE == 0) {
        const int tg = lane >> 3, dq = lane & 7;      // token slot / 16B chunk
        const uint4* tbl = (const uint4*)(ws_ro + OFF_EMBB / 2);
        float acc8[8];
#pragma unroll
        for (int j = 0; j < 8; ++j) acc8[j] = 0.f;

        const int Lfull = L & ~63;
        for (int s0 = 0; s0 < Lfull; s0 += 64) {
            uint4 q[8];
#pragma unroll
            for (int u = 0; u < 8; ++u) {
                int tok = idxr[s0 + u*8 + tg];
                q[u] = tbl[(size_t)tok * 8 + dq];
            }
#pragma unroll
            for (int u = 0; u < 8; ++u) {
                unsigned dw[4] = {q[u].x, q[u].y, q[u].z, q[u].w};
#pragma unroll
                for (int v = 0; v < 4; ++v) {
                    acc8[2*v]   += __uint_as_float(dw[v] << 16);
                    acc8[2*v+1] += __uint_as_float(dw[v] & 0xffff0000u);
                }
            }
        }
        for (int s0 = Lfull; s0 < L; s0 += 8) {
            int s = s0 + tg;
            uint4 q = {0u,0u,0u,0u};
            if (s < L) q = tbl[(size_t)idxr[s] * 8 + dq];
            unsigned dw[4] = {q.x, q.y, q.z, q.w};
#pragma unroll
            for (int v = 0; v < 4; ++v) {
                acc8[2*v]   += __uint_as_float(dw[v] << 16);
                acc8[2*v+1] += __uint_as_float(dw[v] & 0xffff0000u);
            }
        }
#pragma unroll
        for (int j = 0; j < 8; ++j) acc8[j] += __shfl_xor(acc8[j], 8);
#pragma unroll
        for (int j = 0; j < 8; ++j) acc8[j] += __shfl_xor(acc8[j], 16);
#pragma unroll
        for (int j = 0; j < 8; ++j) acc8[j] += __shfl_xor(acc8[j], 32);
        if (lane < 8) {
#pragma unroll
            for (int j = 0; j < 8; ++j) {
                int d = lane*8 + j;
                if (d < 50) pooled_s[wave*144 + d] = f2bf(acc8[j] / Lf);
            }
        }
    } else {
        float accE = 0.f;
        for (int s = 0; s < L; ++s) {
            int tok = idxr[s];
            if (lane < 50) accE += emb[(size_t)tok*50 + lane];
        }
        if (lane < 50) pooled_s[wave*144 + lane] = f2bf(accE / Lf);
    }
    if (lane < 50)
        pooled_s[wave*144 + 50 + lane] = f2bf(pref[(size_t)(L-1)*64 + lane] / Lf);
    __syncthreads();

    // ---- Layer 1 (K=128) from pooled_s, weights in regs
    {
        bf16x8 a1[4];
#pragma unroll
        for (int ks = 0; ks < 4; ++ks)
            a1[ks] = *(const bf16x8*)&pooled_s[row*144 + ks*32 + kq*8];
        f32x4 acc[4];
        float bb[4];
#pragma unroll
        for (int ci = 0; ci < 4; ++ci) {
            bb[ci] = b1[wave*64 + ci*16 + row];
            acc[ci] = (f32x4){0.f,0.f,0.f,0.f};
#pragma unroll
            for (int ks = 0; ks < 4; ++ks) acc[ci] = MFMA16(a1[ks], w1f[ci][ks], acc[ci]);
        }
        store_h(hA, acc, bb, wave, row, kq);
    }
    __syncthreads();

    // ---- Layer 2 (K=512): hA -> hB
    bf16x8 a[16];
    load_afrags(a, hA, row, kq);
    layer512(a, WF2, b2, hB, wave, row, kq, lane);
    __syncthreads();

    // ---- Layer 3 (K=512): hB -> hA
    load_afrags(a, hB, row, kq);
    layer512(a, WF3, b3, hA, wave, row, kq, lane);
    __syncthreads();

    // ---- Final (K=512, N padded 2->16): wave 0 only
    if (wave == 0) {
        load_afrags(a, hA, row, kq);
        const bf16x8* bpf = (const bf16x8*)WFF + lane;
        f32x4 accf = {0.f, 0.f, 0.f, 0.f};
#pragma unroll
        for (int ks = 0; ks < 16; ++ks) {
            bf16x8 bv = bpf[ks*64];
            accf = MFMA16(a[ks], bv, accf);
        }
        if (row < 2 && kq < 2) {
            float bb = bfin[row];
#pragma unroll
            for (int r4 = 0; r4 < 4; ++r4) {
                int m = kq*4 + r4;                   // real rows 0..7
                out[(size_t)(b0 + m) * 2 + row] = accf[r4] + bb;
            }
        }
    }
}

extern "C" void kernel_launch(void* const* d_in, const int* in_sizes, int n_in,
                              void* d_out, int out_size, void* d_ws, size_t ws_size,
                              hipStream_t stream)
{
    const float* emb    = (const float*)d_in[0];
    const float* post   = (const float*)d_in[1];
    const float* W1     = (const float*)d_in[2];
    const float* b1     = (const float*)d_in[3];
    const float* W2     = (const float*)d_in[4];
    const float* b2     = (const float*)d_in[5];
    const float* W3     = (const float*)d_in[6];
    const float* b3     = (const float*)d_in[7];
    const float* Wf     = (const float*)d_in[8];
    const float* bf     = (const float*)d_in[9];
    const int*   seq    = (const int*)d_in[10];
    const int*   seqlen = (const int*)d_in[11];
    const int*   pos    = (const int*)d_in[12];
    float*       out    = (float*)d_out;

    unsigned short* ws = (unsigned short*)d_ws;
    float* pref = (float*)((char*)d_ws + OFF_PREF);
    const int do_emb = (ws_size >= (size_t)WS_NEED) ? 1 : 0;

    prep_convert<<<544, 256, 0, stream>>>(W1, W2, W3, Wf, post, pos, emb,
                                          ws, pref, do_emb);
    if (do_emb)
        dan_fused<0><<<B_ / 8, 512, 0, stream>>>(emb, seq, seqlen, ws, pref,
                                                 b1, b2, b3, bf, out);
    else
        dan_fused<1><<<B_ / 8, 512, 0, stream>>>(emb, seq, seqlen, ws, pref,
                                                 b1, b2, b3, bf, out);
}